// Round 7
// baseline (1414.145 us; speedup 1.0000x reference)
//
#include <hip/hip_runtime.h>
#include <cmath>

// ---------------------------------------------------------------------------
// 3-layer GCN, atomic-free aggregate, bf16 data path, MFMA epilogue.
// R7 core change: SRC-SORTED edge streams + LDS-atomic tile aggregation.
//   Model: warm fused gather ran at 2.56 TB/s == L2 miss-fill ceiling
//   (8 XCD x 128B/cy = 2.46 TB/s). Degree 8 over 8 XCDs -> ~1 read/row/XCD,
//   no intra-XCD reuse, 12.8MB > 4MB L2 -> every read fills. Fix: sort each
//   tile's edges by src (coarse src>>11 bins); all waves sweep src-space in
//   sync -> hot band ~1-3MB is L2-resident in every XCD -> dup reads hit,
//   capacity re-misses vanish. Register per-node accumulation can't consume
//   cross-node src order (deg 8/node), so aggregate via per-wave LDS fp32
//   atomics (stride-67 float rows -> ~2-way bank conflicts only).
// CSR build (4 dispatches):
//   bhist_cvt_k : per-4096-edge-segment LDS hist -> part[seg][512] + x->bf16
//   bscan_k     : 1 block/512t: totals + scan -> bbase/bcur
//   bucket_k    : 1024t: scatter packed (src<<8|dst&255) -> bucket regions
//   fillb_k     : 1024t: per-bucket counting sort by (tile,src>>11) ->
//                 tile_off + eord records (src<<4|node)
// Fused (3 dispatches; R3: never merge -- regalloc collapse): per tile zero
// 16x67f LDS acc -> stage 256 edge records -> 8-deep pipelined row loads
// (uint4 16B/lane, 8 lanes/row, 8 edges/step) -> 8 ds_add_f32/lane ->
// fp32 acc -> bf16 A-frags -> mfma_f32_16x16x32_bf16 -> bias
// (+relu->bf16 | +log_softmax->fp32). W^T in LDS per block.
// ---------------------------------------------------------------------------

#define B1_EPB 4096      // edges per histogram/bucket segment
#define BKT_SH 8         // 256 nodes per bucket
#define CHUNK  256       // staged edge records per wave-chunk
#define PSTRIDE 512      // padded part row stride (coalesced reads)
#define CSH    11        // coarse src shift: 100000>>11 = 48 < 64 bins
#define ASTR   67        // acc float stride/node: (67m+8j+k)%32 spreads banks

typedef __attribute__((ext_vector_type(8))) short bf8;   // 8 x bf16 (4 VGPR)
typedef __attribute__((ext_vector_type(4))) float f4;    // MFMA accumulator

__device__ __forceinline__ unsigned int f2bf(float x) {  // RNE
  unsigned int u = __float_as_uint(x);
  return (u + 0x7FFFu + ((u >> 16) & 1u)) >> 16;
}
__device__ __forceinline__ float bflo(unsigned int u) { return __uint_as_float(u << 16); }
__device__ __forceinline__ float bfhi(unsigned int u) { return __uint_as_float(u & 0xFFFF0000u); }

// ---------------- CSR build ----------------
__global__ void bhist_cvt_k(const int* __restrict__ dsti, int* __restrict__ part,
                            int ne, const float* __restrict__ x,
                            unsigned short* __restrict__ xb, int n4,
                            int nbkt, int nseg) {
  __shared__ int lh[PSTRIDE];
  const int b = blockIdx.x, t = threadIdx.x;
  if (b < nseg) {
    for (int i = t; i < PSTRIDE; i += 256) lh[i] = 0;
    __syncthreads();
    const int base = b * B1_EPB;
    const int m = min(B1_EPB, ne - base);
    for (int i = t; i < m; i += 256) atomicAdd(&lh[dsti[base + i] >> BKT_SH], 1);
    __syncthreads();
    for (int i = t; i < PSTRIDE; i += 256) part[b * PSTRIDE + i] = lh[i];
  }
  const int gid = b * 256 + t, gst = gridDim.x * 256;
  for (int j = gid; j < n4; j += gst) {
    float4 v = ((const float4*)x)[j];
    ushort4 o;
    o.x = (unsigned short)f2bf(v.x); o.y = (unsigned short)f2bf(v.y);
    o.z = (unsigned short)f2bf(v.z); o.w = (unsigned short)f2bf(v.w);
    ((ushort4*)xb)[j] = o;
  }
}

// Single block, 512 threads: per-bucket totals (8-deep ILP) + scan.
__global__ void bscan_k(const int* __restrict__ part, int* __restrict__ bbase,
                        int* __restrict__ bcur, int nbkt, int nseg, int ne) {
  __shared__ int sh[512];
  const int t = threadIdx.x;
  int s0 = 0, s1 = 0, s2 = 0, s3 = 0, s4 = 0, s5 = 0, s6 = 0, s7 = 0;
  int b = 0;
  for (; b + 7 < nseg; b += 8) {
    s0 += part[(b + 0) * PSTRIDE + t];
    s1 += part[(b + 1) * PSTRIDE + t];
    s2 += part[(b + 2) * PSTRIDE + t];
    s3 += part[(b + 3) * PSTRIDE + t];
    s4 += part[(b + 4) * PSTRIDE + t];
    s5 += part[(b + 5) * PSTRIDE + t];
    s6 += part[(b + 6) * PSTRIDE + t];
    s7 += part[(b + 7) * PSTRIDE + t];
  }
  for (; b < nseg; ++b) s0 += part[b * PSTRIDE + t];
  const int s = ((s0 + s1) + (s2 + s3)) + ((s4 + s5) + (s6 + s7));
  sh[t] = s; __syncthreads();
  for (int o = 1; o < 512; o <<= 1) {
    int v = (t >= o) ? sh[t - o] : 0; __syncthreads();
    sh[t] += v; __syncthreads();
  }
  if (t < nbkt) { int e = sh[t] - s; bbase[t] = e; bcur[t] = e; }
  if (t == 0) bbase[nbkt] = ne;
}

// 1024 threads: scatter packed (src<<8 | dst&255) into per-bucket regions.
__global__ void bucket_k(const int* __restrict__ srci, const int* __restrict__ dsti,
                         const int* __restrict__ part, int* __restrict__ bcur,
                         unsigned int* __restrict__ ebuf, int ne, int nbkt) {
  __shared__ int lcur[512], lbase[512];
  const int t = threadIdx.x;
  const int base = blockIdx.x * B1_EPB;
  const int m = min(B1_EPB, ne - base);
  for (int i = t; i < nbkt; i += 1024) {
    const int c = part[blockIdx.x * PSTRIDE + i];
    lbase[i] = c ? atomicAdd(&bcur[i], c) : 0;
    lcur[i] = 0;
  }
  __syncthreads();
  for (int i = t; i < m; i += 1024) {
    const int s = srci[base + i], d = dsti[base + i];
    const int b = d >> BKT_SH;
    const int p = lbase[b] + atomicAdd(&lcur[b], 1);
    ebuf[p] = ((unsigned)s << 8) | (unsigned)(d & ((1 << BKT_SH) - 1));
  }
}

// 1024 threads, one block per 256-node bucket: counting sort by key =
// (tile-in-bucket(4b) << 6) | (src >> CSH  (<=48, 6b)) -> 1024 bins.
// Emits tile_off[tile] (start of each 16-node tile's segment, src-sorted
// within) and eord records (src<<4 | node-in-tile).
__global__ void fillb_k(const unsigned int* __restrict__ ebuf,
                        const int* __restrict__ bbase,
                        int* __restrict__ tile_off, unsigned int* __restrict__ eord,
                        int ntiles, int ne, int nbkt) {
  __shared__ int lcnt[1024], lpre[1024], lcur[1024];
  const int b = blockIdx.x, t = threadIdx.x;
  const int start = bbase[b], end = bbase[b + 1];
  lcnt[t] = 0; __syncthreads();
  for (int i = start + t; i < end; i += 1024) {
    const unsigned e = ebuf[i];
    const int key = (int)(((e >> 4) & 15u) << 6) | (int)((e >> 8) >> CSH);
    atomicAdd(&lcnt[key], 1);
  }
  __syncthreads();
  const int x = lcnt[t];
  lpre[t] = x; __syncthreads();
  for (int o = 1; o < 1024; o <<= 1) {
    int v = (t >= o) ? lpre[t - o] : 0; __syncthreads();
    lpre[t] += v; __syncthreads();
  }
  const int excl = start + lpre[t] - x;
  lcur[t] = excl;
  if ((t & 63) == 0) {                       // first bin of each tile
    const int tl = b * 16 + (t >> 6);
    if (tl < ntiles) tile_off[tl] = excl;
  }
  if (b == nbkt - 1 && t == 0) tile_off[ntiles] = ne;
  __syncthreads();
  for (int i = start + t; i < end; i += 1024) {
    const unsigned e = ebuf[i];
    const int key = (int)(((e >> 4) & 15u) << 6) | (int)((e >> 8) >> CSH);
    const int p = atomicAdd(&lcur[key], 1);
    eord[p] = ((e >> 8) << 4) | (e & 15u);   // src<<4 | node-in-tile
  }
}

// ---------------- fused gather + MFMA GEMM (+relu | +log_softmax) ----------
// One wave per 16-node tile (2 tiles/wave at 784 blocks). Tile edges are
// src-sorted; 8-lane groups each process one edge/step, 8 steps (64 edges)
// pipelined -> 8 uint4 loads in flight. Accumulate into per-wave LDS fp32
// acc[16][ASTR] via atomicAdd (same-wave only; LDS pipe is in-order/wave).
// Then fp32 acc -> bf16 A-frags -> MFMA. C layout: col=lane&15, row=quad*4+reg.
template <int DOUT, bool LS>
__launch_bounds__(256, 4)
__global__ void fused_k(const unsigned short* __restrict__ in,
                        const int* __restrict__ tile_off, const unsigned int* __restrict__ eord,
                        const float* __restrict__ Wm, const float* __restrict__ bin,
                        void* __restrict__ outp, int n) {
  constexpr int NT = (DOUT + 15) / 16;
  const int lane  = threadIdx.x & 63;
  const int wslot = threadIdx.x >> 6;
  const int quad  = lane >> 4;
  const int f16i  = lane & 15;
  const int g     = lane >> 3;         // 8-lane group id (edge slot)
  const int j8    = lane & 7;          // uint4 index within row

  __shared__ float accs[4][16 * ASTR];
  __shared__ int  sidx[4][CHUNK];
  __shared__ unsigned short Wt[64 * 72];   // [c][k] bf16, 72-short rows
  float* accw = accs[wslot];
  int*   sid  = sidx[wslot];

  // ---- stage W^T -> LDS (once per block); zero-fill pads c >= DOUT ----
  {
    const int t = threadIdx.x;
    for (int i = t; i < 64 * 72; i += 256) Wt[i] = 0;
    __syncthreads();
    for (int i = t; i < 64 * DOUT; i += 256) {
      const int k = i / DOUT, c = i - k * DOUT;   // Wm row-major [64][DOUT]
      Wt[c * 72 + k] = (unsigned short)f2bf(Wm[i]);
    }
  }
  float bc[NT];
#pragma unroll
  for (int t = 0; t < NT; ++t) {
    const int c = t * 16 + f16i;
    bc[t] = (c < DOUT) ? bin[c] : 0.f;
  }
  __syncthreads();

  const uint4* in4 = (const uint4*)in;     // bf16 row = 8 x uint4 (128B)
  const int wid = (int)((blockIdx.x * blockDim.x + threadIdx.x) >> 6);
  const int nwv = (int)((gridDim.x * blockDim.x) >> 6);
  const int ntiles = (n + 15) >> 4;

  for (int tile = wid; tile < ntiles; tile += nwv) {
    const int v0 = tile << 4;
    const int base = tile_off[tile];
    const int end_ = tile_off[tile + 1];

    // zero per-wave fp32 accumulator
    for (int i = lane; i < 16 * ASTR; i += 64) accw[i] = 0.f;
    asm volatile("s_waitcnt lgkmcnt(0)" ::: "memory");

    for (int off = base; off < end_; off += CHUNK) {
      const int cend = min(end_, off + CHUNK);
      const int nL = cend - off;
      // stage records: coalesced, guarded rounds
#pragma unroll
      for (int k = 0; k < CHUNK / 64; ++k) {
        const int p = off + lane + k * 64;
        if (p < cend) sid[lane + k * 64] = (int)eord[p];
      }
      asm volatile("s_waitcnt lgkmcnt(0)" ::: "memory");   // cross-lane LDS RAW

      for (int blk = 0; blk < nL; blk += 64) {
        uint4 q[8];
        int   mm[8];
#pragma unroll
        for (int k = 0; k < 8; ++k) {
          const int idx = blk + k * 8 + g;
          const int lofs = min(idx, nL - 1);            // clamp LDS read
          const unsigned rec = (unsigned)sid[lofs];     // 8-lane broadcast
          mm[k] = (int)(rec & 15u);
          q[k] = in4[(size_t)(rec >> 4) * 8 + j8];      // 8 loads in flight
          if (idx >= nL) q[k] = make_uint4(0u, 0u, 0u, 0u);  // add 0 = no-op
        }
#pragma unroll
        for (int k = 0; k < 8; ++k) {
          float* ap = accw + mm[k] * ASTR + j8 * 8;
          atomicAdd(ap + 0, bflo(q[k].x)); atomicAdd(ap + 1, bfhi(q[k].x));
          atomicAdd(ap + 2, bflo(q[k].y)); atomicAdd(ap + 3, bfhi(q[k].y));
          atomicAdd(ap + 4, bflo(q[k].z)); atomicAdd(ap + 5, bfhi(q[k].z));
          atomicAdd(ap + 6, bflo(q[k].w)); atomicAdd(ap + 7, bfhi(q[k].w));
        }
      }
    }
    asm volatile("s_waitcnt lgkmcnt(0)" ::: "memory");   // drain ds_adds

    // ---- fp32 acc -> bf16 A fragments ----
    const float* ar = accw + f16i * ASTR + quad * 8;
    bf8 a0, a1;
#pragma unroll
    for (int j = 0; j < 8; ++j) {
      a0[j] = (short)f2bf(ar[j]);
      a1[j] = (short)f2bf(ar[32 + j]);
    }

    // ---- MFMA: [16 x 64] @ [64 x DOUT], B fragments from LDS W^T ----
    f4 acc2[NT];
#pragma unroll
    for (int t = 0; t < NT; ++t) {
      const unsigned short* wp = Wt + (t * 16 + f16i) * 72 + quad * 8;
      bf8 w0 = *(const bf8*)(wp);
      bf8 w1 = *(const bf8*)(wp + 32);
      f4 z = {0.f, 0.f, 0.f, 0.f};
      acc2[t] = __builtin_amdgcn_mfma_f32_16x16x32_bf16(a0, w0, z, 0, 0, 0);
      acc2[t] = __builtin_amdgcn_mfma_f32_16x16x32_bf16(a1, w1, acc2[t], 0, 0, 0);
    }

    // ---- epilogue ----
    if (!LS) {
      unsigned short* ob = (unsigned short*)outp;
#pragma unroll
      for (int t = 0; t < NT; ++t)
#pragma unroll
        for (int j = 0; j < 4; ++j) {
          const int v = v0 + quad * 4 + j;
          if (v < n) {
            float val = acc2[t][j] + bc[t];
            ob[(size_t)v * 64 + t * 16 + f16i] =
                (unsigned short)f2bf(fmaxf(val, 0.f));
          }
        }
    } else {
      float* ob = (float*)outp;
      float val[NT][4];
#pragma unroll
      for (int t = 0; t < NT; ++t)
#pragma unroll
        for (int j = 0; j < 4; ++j) val[t][j] = acc2[t][j] + bc[t];
#pragma unroll
      for (int j = 0; j < 4; ++j) {
        float mx = -INFINITY;
#pragma unroll
        for (int t = 0; t < NT; ++t)
          if (t * 16 + f16i < DOUT) mx = fmaxf(mx, val[t][j]);
#pragma unroll
        for (int o = 1; o <= 8; o <<= 1) mx = fmaxf(mx, __shfl_xor(mx, o, 64));
        float sm = 0.f;
#pragma unroll
        for (int t = 0; t < NT; ++t)
          if (t * 16 + f16i < DOUT) sm += __expf(val[t][j] - mx);
#pragma unroll
        for (int o = 1; o <= 8; o <<= 1) sm += __shfl_xor(sm, o, 64);
        const float lse = mx + __logf(sm);
        const int v = v0 + quad * 4 + j;
        if (v < n) {
#pragma unroll
          for (int t = 0; t < NT; ++t) {
            const int c = t * 16 + f16i;
            if (c < DOUT) ob[(size_t)v * DOUT + c] = val[t][j] - lse;
          }
        }
      }
    }
  }
}

extern "C" void kernel_launch(void* const* d_in, const int* in_sizes, int n_in,
                              void* d_out, int out_size, void* d_ws, size_t ws_size,
                              hipStream_t stream) {
  const float* x  = (const float*)d_in[0];
  const int*   ei = (const int*)d_in[1];   // [2, E] int32, row-major
  const float* W1 = (const float*)d_in[2];
  const float* b1 = (const float*)d_in[3];
  const float* W2 = (const float*)d_in[4];
  const float* b2 = (const float*)d_in[5];
  const float* W3 = (const float*)d_in[6];
  const float* b3 = (const float*)d_in[7];
  float* outp = (float*)d_out;

  const int n  = in_sizes[0] / 64;   // 100000
  const int ne = in_sizes[1] / 2;    // 800000
  const int* srci = ei;
  const int* dsti = ei + ne;
  const int nbkt = (n + (1 << BKT_SH) - 1) >> BKT_SH;   // 391
  const int nseg = (ne + B1_EPB - 1) / B1_EPB;          // 196
  const int ntiles = (n + 15) >> 4;                     // 6250

  const size_t N64 = (size_t)n * 64;
  unsigned short* xb   = (unsigned short*)d_ws;   // N*64 bf16
  unsigned short* bufA = xb + N64;                // N*64 bf16 (h1)
  unsigned short* bufB = bufA + N64;              // N*64 bf16 (h2)
  unsigned int* ebuf = (unsigned int*)(bufB + N64);  // E packed (src<<8|dst&255)
  int* tile_off = (int*)(ebuf + ne);              // ntiles+1
  int* part     = tile_off + ntiles + 1;          // nseg*PSTRIDE
  int* bbase    = part + nseg * PSTRIDE;          // nbkt+1
  int* bcur     = bbase + nbkt + 1;               // nbkt
  unsigned int* eord = (unsigned int*)(bcur + nbkt);  // E (src<<4|node)

  const int TB = 256;
  const int fus_blocks = 784;   // 3136 waves, all co-resident; 2 tiles/wave

  // ---- CSR build + x->bf16 (4 dispatches) ----
  bhist_cvt_k<<<784, TB, 0, stream>>>(dsti, part, ne, x, xb, (int)(N64 / 4), nbkt, nseg);
  bscan_k<<<1, 512, 0, stream>>>(part, bbase, bcur, nbkt, nseg, ne);
  bucket_k<<<nseg, 1024, 0, stream>>>(srci, dsti, part, bcur, ebuf, ne, nbkt);
  fillb_k<<<nbkt, 1024, 0, stream>>>(ebuf, bbase, tile_off, eord, ntiles, ne, nbkt);

  // ---- fused layers ----
  fused_k<64, false><<<fus_blocks, TB, 0, stream>>>(xb,   tile_off, eord, W1, b1, bufA, n);
  fused_k<64, false><<<fus_blocks, TB, 0, stream>>>(bufA, tile_off, eord, W2, b2, bufB, n);
  fused_k<47, true ><<<fus_blocks, TB, 0, stream>>>(bufB, tile_off, eord, W3, b3, outp, n);
}

// Round 8
// 204.433 us; speedup vs baseline: 6.9174x; 6.9174x over previous
//
#include <hip/hip_runtime.h>
#include <cmath>

// ---------------------------------------------------------------------------
// 3-layer GCN, atomic-free aggregate, bf16 data path, MFMA epilogue.
// == R6 verified configuration (203.7us) restored after R7's LDS-atomic
// experiment (440us/layer: VGPR collapsed to 48, ds_add_f32 ~10x register
// accumulation; register per-node accumulation is non-negotiable). ==
// Ledger: fused gather runs at ~2.5TB/s == 8-XCD L2 miss-fill ceiling
// (1 compulsory fill/row/XCD at degree 8 = dst-stationary optimum);
// per-wave structure changes are neutral (R1/R4/R5), structural rewrites
// collapse codegen (R3/R7). Remaining theoretical lever: <4MB/XCD plane
// split with temporal pass alignment -- high risk, not taken.
// CSR build (4 dispatches, no memset):
//   bhist_cvt_k : per-4096-edge-segment LDS hist -> part[seg][512] + x->bf16
//   bscan_k     : 1 block/512t: totals (8-deep ILP) + 512-wide scan
//   bucket_k    : 1024t: scatter packed (src<<8|dst&255) -> bucket regions
//   fillb_k     : 1024t: per-bucket LDS hist + scan -> row_off + ssrc
// Fused: 784 blocks (3136 waves co-resident), 2 tiles/wave, pipelined
// row_off + first-chunk prefetch; uint4 16B loads, 8 lanes/row, 16 edges in
// flight; halves merged by shfl_xor(8); fp32 acc -> bf16 -> MFMA -> bias
// (+relu->bf16 | +log_softmax->fp32). W^T in LDS per block.
// ---------------------------------------------------------------------------

#define B1_EPB 4096      // edges per histogram/bucket segment
#define BKT_SH 8         // 256 nodes per bucket
#define CHUNK  256       // staged edge indices per wave-chunk
#define PSTRIDE 512      // padded part row stride (coalesced reads)

typedef __attribute__((ext_vector_type(8))) short bf8;   // 8 x bf16 (4 VGPR)
typedef __attribute__((ext_vector_type(4))) float f4;    // MFMA accumulator

__device__ __forceinline__ unsigned int f2bf(float x) {  // RNE
  unsigned int u = __float_as_uint(x);
  return (u + 0x7FFFu + ((u >> 16) & 1u)) >> 16;
}
__device__ __forceinline__ float bflo(unsigned int u) { return __uint_as_float(u << 16); }
__device__ __forceinline__ float bfhi(unsigned int u) { return __uint_as_float(u & 0xFFFF0000u); }

// ---------------- CSR build ----------------
__global__ void bhist_cvt_k(const int* __restrict__ dsti, int* __restrict__ part,
                            int ne, const float* __restrict__ x,
                            unsigned short* __restrict__ xb, int n4,
                            int nbkt, int nseg) {
  __shared__ int lh[PSTRIDE];
  const int b = blockIdx.x, t = threadIdx.x;
  if (b < nseg) {
    for (int i = t; i < PSTRIDE; i += 256) lh[i] = 0;
    __syncthreads();
    const int base = b * B1_EPB;
    const int m = min(B1_EPB, ne - base);
    for (int i = t; i < m; i += 256) atomicAdd(&lh[dsti[base + i] >> BKT_SH], 1);
    __syncthreads();
    for (int i = t; i < PSTRIDE; i += 256) part[b * PSTRIDE + i] = lh[i];
  }
  const int gid = b * 256 + t, gst = gridDim.x * 256;
  for (int j = gid; j < n4; j += gst) {
    float4 v = ((const float4*)x)[j];
    ushort4 o;
    o.x = (unsigned short)f2bf(v.x); o.y = (unsigned short)f2bf(v.y);
    o.z = (unsigned short)f2bf(v.z); o.w = (unsigned short)f2bf(v.w);
    ((ushort4*)xb)[j] = o;
  }
}

// Single block, 512 threads: per-bucket totals (8-deep ILP, coalesced rows)
// then 512-wide scan -> bbase/bcur.
__global__ void bscan_k(const int* __restrict__ part, int* __restrict__ bbase,
                        int* __restrict__ bcur, int nbkt, int nseg, int ne) {
  __shared__ int sh[512];
  const int t = threadIdx.x;
  int s0 = 0, s1 = 0, s2 = 0, s3 = 0, s4 = 0, s5 = 0, s6 = 0, s7 = 0;
  int b = 0;
  for (; b + 7 < nseg; b += 8) {
    s0 += part[(b + 0) * PSTRIDE + t];
    s1 += part[(b + 1) * PSTRIDE + t];
    s2 += part[(b + 2) * PSTRIDE + t];
    s3 += part[(b + 3) * PSTRIDE + t];
    s4 += part[(b + 4) * PSTRIDE + t];
    s5 += part[(b + 5) * PSTRIDE + t];
    s6 += part[(b + 6) * PSTRIDE + t];
    s7 += part[(b + 7) * PSTRIDE + t];
  }
  for (; b < nseg; ++b) s0 += part[b * PSTRIDE + t];
  const int s = ((s0 + s1) + (s2 + s3)) + ((s4 + s5) + (s6 + s7));
  sh[t] = s; __syncthreads();
  for (int o = 1; o < 512; o <<= 1) {
    int v = (t >= o) ? sh[t - o] : 0; __syncthreads();
    sh[t] += v; __syncthreads();
  }
  if (t < nbkt) { int e = sh[t] - s; bbase[t] = e; bcur[t] = e; }
  if (t == 0) bbase[nbkt] = ne;
}

// 1024 threads: scatter packed (src<<8 | dst&255) into per-bucket regions.
// Counts read from part. 4B records halve store traffic vs uint2.
__global__ void bucket_k(const int* __restrict__ srci, const int* __restrict__ dsti,
                         const int* __restrict__ part, int* __restrict__ bcur,
                         unsigned int* __restrict__ ebuf, int ne, int nbkt) {
  __shared__ int lcur[512], lbase[512];
  const int t = threadIdx.x;
  const int base = blockIdx.x * B1_EPB;
  const int m = min(B1_EPB, ne - base);
  for (int i = t; i < nbkt; i += 1024) {
    const int c = part[blockIdx.x * PSTRIDE + i];
    lbase[i] = c ? atomicAdd(&bcur[i], c) : 0;
    lcur[i] = 0;
  }
  __syncthreads();
  for (int i = t; i < m; i += 1024) {
    const int s = srci[base + i], d = dsti[base + i];
    const int b = d >> BKT_SH;
    const int p = lbase[b] + atomicAdd(&lcur[b], 1);
    ebuf[p] = ((unsigned)s << 8) | (unsigned)(d & ((1 << BKT_SH) - 1));
  }
}

// 1024 threads, one block per 256-node bucket: LDS hist of (dst&255) ->
// 256-wide scan (threads <256) -> row_off + scatter src into ssrc region.
__global__ void fillb_k(const unsigned int* __restrict__ ebuf,
                        const int* __restrict__ bbase,
                        int* __restrict__ row_off, int* __restrict__ ssrc,
                        int n, int ne) {
  __shared__ int lcnt[256], lpre[256], lcur[256];
  const int b = blockIdx.x, t = threadIdx.x;
  const int v0 = b << BKT_SH;
  const int nv = min(1 << BKT_SH, n - v0);
  const int start = bbase[b], end = bbase[b + 1];
  if (t < 256) lcnt[t] = 0;
  __syncthreads();
  for (int i = start + t; i < end; i += 1024)
    atomicAdd(&lcnt[ebuf[i] & ((1 << BKT_SH) - 1)], 1);
  __syncthreads();
  int x = 0;
  if (t < 256) { x = lcnt[t]; lpre[t] = x; }
  __syncthreads();
  for (int o = 1; o < 256; o <<= 1) {
    int v = 0;
    if (t < 256 && t >= o) v = lpre[t - o];
    __syncthreads();
    if (t < 256) lpre[t] += v;
    __syncthreads();
  }
  if (t < 256) {
    const int excl = start + lpre[t] - x;
    lcur[t] = excl;
    if (t < nv) row_off[v0 + t] = excl;
    if (t == 0) row_off[v0 + nv] = end;   // == next bucket's base (or ne)
  }
  __syncthreads();
  for (int i = start + t; i < end; i += 1024) {
    const unsigned int e = ebuf[i];
    const int p = atomicAdd(&lcur[e & ((1 << BKT_SH) - 1)], 1);
    ssrc[p] = (int)(e >> 8);
  }
}

// ---------------- fused gather + MFMA GEMM (+relu | +log_softmax) ----------
// 2 tiles/wave, software-pipelined row_off + first-chunk prefetch; uint4 16B
// loads, 8 lanes/row, 16 edges in flight; halves merged by shfl_xor(8).
// C layout: col = lane&15, row = quad*4 + reg.
template <int DOUT, bool LS>
__launch_bounds__(256, 4)
__global__ void fused_k(const unsigned short* __restrict__ in,
                        const int* __restrict__ row_off, const int* __restrict__ ssrc,
                        const float* __restrict__ Wm, const float* __restrict__ bin,
                        void* __restrict__ outp, int n) {
  constexpr int NT = (DOUT + 15) / 16;
  const int lane  = threadIdx.x & 63;
  const int wslot = threadIdx.x >> 6;
  const int quad  = lane >> 4;
  const int f16i  = lane & 15;
  const int hw    = (f16i >> 3) & 1;   // half within quarter (edge parity)
  const int j8    = f16i & 7;          // uint4 index within row (cols 8*j8..+7)

  __shared__ char rows_raw[4][16 * 144];
  __shared__ int  sidx[4][CHUNK];
  __shared__ unsigned short Wt[64 * 72];   // [c][k] bf16, 72-short (144B) rows
  char* my  = rows_raw[wslot];
  int*  sid = sidx[wslot];

  // ---- stage W^T -> LDS (once per block); zero-fill pads c >= DOUT ----
  {
    const int t = threadIdx.x;
    for (int i = t; i < 64 * 72; i += 256) Wt[i] = 0;
    __syncthreads();
    for (int i = t; i < 64 * DOUT; i += 256) {
      const int k = i / DOUT, c = i - k * DOUT;   // Wm row-major [64][DOUT]
      Wt[c * 72 + k] = (unsigned short)f2bf(Wm[i]);
    }
  }
  float bc[NT];
#pragma unroll
  for (int t = 0; t < NT; ++t) {
    const int c = t * 16 + f16i;
    bc[t] = (c < DOUT) ? bin[c] : 0.f;
  }
  __syncthreads();

  const uint4* in4 = (const uint4*)in;     // bf16 row = 8 x uint4 (128B)
  const int wid = (int)((blockIdx.x * blockDim.x + threadIdx.x) >> 6);
  const int nwv = (int)((gridDim.x * blockDim.x) >> 6);
  const int ntiles = (n + 15) >> 4;

  bool have_pref = false;                  // sid holds next tile's chunk 0?
  int ro_l = (wid < ntiles)
                 ? row_off[min((wid << 4) + min(lane, 16), n)] : 0;

  for (int tile = wid; tile < ntiles; tile += nwv) {
    const int tnext = tile + nwv;
    int ro_next = 0;
    if (tnext < ntiles)                    // issue early; consumed late
      ro_next = row_off[min((tnext << 4) + min(lane, 16), n)];

    const int v0 = tile << 4;
    const int base     = __shfl(ro_l, 0, 64);
    const int tile_end = __shfl(ro_l, 16, 64);
    int ns[4], nE[4];
#pragma unroll
    for (int r = 0; r < 4; ++r) {
      const int m = quad * 4 + r;
      ns[r] = __shfl(ro_l, m, 64);
      nE[r] = __shfl(ro_l, m + 1, 64);
    }

    float acc[4][8];
#pragma unroll
    for (int r = 0; r < 4; ++r)
#pragma unroll
      for (int i = 0; i < 8; ++i) acc[r][i] = 0.f;

    for (int off = base; off < tile_end; off += CHUNK) {
      const int cend = min(tile_end, off + CHUNK);
      const int nL = cend - off;
      if (!(have_pref && off == base)) {   // chunk 0 may be pre-staged
#pragma unroll
        for (int k = 0; k < CHUNK / 64; ++k) {
          const int p = off + lane + k * 64;
          if (p < cend) sid[lane + k * 64] = ssrc[p];
        }
      }
      asm volatile("s_waitcnt lgkmcnt(0)" ::: "memory");   // cross-lane LDS RAW

#pragma unroll
      for (int r = 0; r < 4; ++r) {
        const int ls = max(ns[r], off), le = min(nE[r], cend);
        for (int c = ls; c < le; c += 16) {
          uint4 q[8];
#pragma unroll
          for (int k = 0; k < 8; ++k) {
            const int e = c + (k << 1) + hw;             // 16 edges in flight
            const int lofs = min(e - off, nL - 1);       // clamp LDS read
            const int s = sid[lofs];                      // 8-lane broadcast
            q[k] = (e < le) ? in4[(size_t)s * 8 + j8]
                            : make_uint4(0u, 0u, 0u, 0u);
          }
#pragma unroll
          for (int k = 0; k < 8; ++k) {
            acc[r][0] += bflo(q[k].x); acc[r][1] += bfhi(q[k].x);
            acc[r][2] += bflo(q[k].y); acc[r][3] += bfhi(q[k].y);
            acc[r][4] += bflo(q[k].z); acc[r][5] += bfhi(q[k].z);
            acc[r][6] += bflo(q[k].w); acc[r][7] += bfhi(q[k].w);
          }
        }
      }
    }

    // ---- prefetch next tile's first index chunk (hides under epilogue) ----
    bool pref_ok = false;
    if (tnext < ntiles) {
      const int base_n = __shfl(ro_next, 0, 64);
      const int tend_n = __shfl(ro_next, 16, 64);
      const int cend_n = min(tend_n, base_n + CHUNK);
#pragma unroll
      for (int k = 0; k < CHUNK / 64; ++k) {
        const int p = base_n + lane + k * 64;
        if (p < cend_n) sid[lane + k * 64] = ssrc[p];
      }
      pref_ok = true;
    }

    // merge halves + pack rows -> LDS (8 lanes write 16B each = 128B row)
#pragma unroll
    for (int r = 0; r < 4; ++r) {
#pragma unroll
      for (int i = 0; i < 8; ++i) acc[r][i] += __shfl_xor(acc[r][i], 8, 64);
      if (hw == 0) {
        const int m = quad * 4 + r;
        uint4 p;
        p.x = f2bf(acc[r][0]) | (f2bf(acc[r][1]) << 16);
        p.y = f2bf(acc[r][2]) | (f2bf(acc[r][3]) << 16);
        p.z = f2bf(acc[r][4]) | (f2bf(acc[r][5]) << 16);
        p.w = f2bf(acc[r][6]) | (f2bf(acc[r][7]) << 16);
        *(uint4*)(my + m * 144 + j8 * 16) = p;
      }
    }
    asm volatile("s_waitcnt lgkmcnt(0)" ::: "memory");   // cross-lane LDS RAW

    // ---- MFMA: [16 x 64] @ [64 x DOUT], B fragments from LDS W^T ----
    bf8 a0 = *(const bf8*)(my + f16i * 144 + quad * 16);        // K 0..31
    bf8 a1 = *(const bf8*)(my + f16i * 144 + quad * 16 + 64);   // K 32..63
    f4 acc2[NT];
#pragma unroll
    for (int t = 0; t < NT; ++t) {
      const unsigned short* wp = Wt + (t * 16 + f16i) * 72 + quad * 8;
      bf8 w0 = *(const bf8*)(wp);
      bf8 w1 = *(const bf8*)(wp + 32);
      f4 z = {0.f, 0.f, 0.f, 0.f};
      acc2[t] = __builtin_amdgcn_mfma_f32_16x16x32_bf16(a0, w0, z, 0, 0, 0);
      acc2[t] = __builtin_amdgcn_mfma_f32_16x16x32_bf16(a1, w1, acc2[t], 0, 0, 0);
    }

    // ---- epilogue ----
    if (!LS) {
      unsigned short* ob = (unsigned short*)outp;
#pragma unroll
      for (int t = 0; t < NT; ++t)
#pragma unroll
        for (int j = 0; j < 4; ++j) {
          const int v = v0 + quad * 4 + j;
          if (v < n) {
            float val = acc2[t][j] + bc[t];
            ob[(size_t)v * 64 + t * 16 + f16i] =
                (unsigned short)f2bf(fmaxf(val, 0.f));
          }
        }
    } else {
      float* ob = (float*)outp;
      float val[NT][4];
#pragma unroll
      for (int t = 0; t < NT; ++t)
#pragma unroll
        for (int j = 0; j < 4; ++j) val[t][j] = acc2[t][j] + bc[t];
#pragma unroll
      for (int j = 0; j < 4; ++j) {
        float mx = -INFINITY;
#pragma unroll
        for (int t = 0; t < NT; ++t)
          if (t * 16 + f16i < DOUT) mx = fmaxf(mx, val[t][j]);
#pragma unroll
        for (int o = 1; o <= 8; o <<= 1) mx = fmaxf(mx, __shfl_xor(mx, o, 64));
        float sm = 0.f;
#pragma unroll
        for (int t = 0; t < NT; ++t)
          if (t * 16 + f16i < DOUT) sm += __expf(val[t][j] - mx);
#pragma unroll
        for (int o = 1; o <= 8; o <<= 1) sm += __shfl_xor(sm, o, 64);
        const float lse = mx + __logf(sm);
        const int v = v0 + quad * 4 + j;
        if (v < n) {
#pragma unroll
          for (int t = 0; t < NT; ++t) {
            const int c = t * 16 + f16i;
            if (c < DOUT) ob[(size_t)v * DOUT + c] = val[t][j] - lse;
          }
        }
      }
    }

    have_pref = pref_ok;
    ro_l = ro_next;
  }
}

extern "C" void kernel_launch(void* const* d_in, const int* in_sizes, int n_in,
                              void* d_out, int out_size, void* d_ws, size_t ws_size,
                              hipStream_t stream) {
  const float* x  = (const float*)d_in[0];
  const int*   ei = (const int*)d_in[1];   // [2, E] int32, row-major
  const float* W1 = (const float*)d_in[2];
  const float* b1 = (const float*)d_in[3];
  const float* W2 = (const float*)d_in[4];
  const float* b2 = (const float*)d_in[5];
  const float* W3 = (const float*)d_in[6];
  const float* b3 = (const float*)d_in[7];
  float* outp = (float*)d_out;

  const int n  = in_sizes[0] / 64;   // 100000
  const int ne = in_sizes[1] / 2;    // 800000
  const int* srci = ei;
  const int* dsti = ei + ne;
  const int nbkt = (n + (1 << BKT_SH) - 1) >> BKT_SH;   // 391
  const int nseg = (ne + B1_EPB - 1) / B1_EPB;          // 196

  const size_t N64 = (size_t)n * 64;
  unsigned short* xb   = (unsigned short*)d_ws;   // N*64 bf16
  unsigned short* bufA = xb + N64;                // N*64 bf16 (h1)
  unsigned short* bufB = bufA + N64;              // N*64 bf16 (h2)
  unsigned int* ebuf = (unsigned int*)(bufB + N64);  // E packed (src<<8|dst&255)
  int* row_off  = (int*)(ebuf + ne);              // N+1
  int* part     = row_off + n + 1;                // nseg*PSTRIDE
  int* bbase    = part + nseg * PSTRIDE;          // nbkt+1
  int* bcur     = bbase + nbkt + 1;               // nbkt
  int* ssrc     = bcur + nbkt;                    // E

  const int TB = 256;
  const int fus_blocks = 784;   // 3136 waves, all co-resident; 2 tiles/wave

  // ---- CSR build + x->bf16 (4 dispatches) ----
  bhist_cvt_k<<<784, TB, 0, stream>>>(dsti, part, ne, x, xb, (int)(N64 / 4), nbkt, nseg);
  bscan_k<<<1, 512, 0, stream>>>(part, bbase, bcur, nbkt, nseg, ne);
  bucket_k<<<nseg, 1024, 0, stream>>>(srci, dsti, part, bcur, ebuf, ne, nbkt);
  fillb_k<<<nbkt, 1024, 0, stream>>>(ebuf, bbase, row_off, ssrc, n, ne);

  // ---- fused layers ----
  fused_k<64, false><<<fus_blocks, TB, 0, stream>>>(xb,   row_off, ssrc, W1, b1, bufA, n);
  fused_k<64, false><<<fus_blocks, TB, 0, stream>>>(bufA, row_off, ssrc, W2, b2, bufB, n);
  fused_k<47, true ><<<fus_blocks, TB, 0, stream>>>(bufB, row_off, ssrc, W3, b3, outp, n);
}

// Round 9
// 195.636 us; speedup vs baseline: 7.2285x; 1.0450x over previous
//
#include <hip/hip_runtime.h>
#include <cmath>

// ---------------------------------------------------------------------------
// 3-layer GCN, atomic-free aggregate, FP8 feature rows, MFMA epilogue.
// R9 change vs verified R6 (204us): gathered feature rows stored as fp8
// e4m3 (OCP, native gfx950 cvt) -> row 128B -> 64B. Fused gather is pinned
// at the 8-XCD L2 fill ceiling (~2.5TB/s line fills, 1 compulsory fill/row/
// XCD at degree 8); halving row bytes halves fill traffic AND distinct-line
// count (2 rows/128B line). Numerics: fp32 edge accumulation, bf16 MFMA,
// fp32 log_softmax unchanged -- only stored feature precision drops.
// Everything else is byte-for-byte R6 (single-variable experiment; q[8]
// uint4->uint2 also cuts 16 VGPRs, away from the R3/R7 collapse cliff).
// CSR build (4 dispatches, no memset):
//   bhist_cvt_k : per-4096-edge-segment LDS hist -> part[seg][512] + x->fp8
//   bscan_k     : 1 block/512t: totals (8-deep ILP) + 512-wide scan
//   bucket_k    : 1024t: scatter packed (src<<8|dst&255) -> bucket regions
//   fillb_k     : 1024t: per-bucket LDS hist + scan -> row_off + ssrc
// Fused: 784 blocks (3136 waves co-resident), 2 tiles/wave, pipelined
// row_off + first-chunk prefetch; uint2 8B loads, 8 lanes/row, 16 edges in
// flight; halves merged by shfl_xor(8); fp32 acc -> bf16 -> MFMA -> bias
// (+relu->fp8 | +log_softmax->fp32). W^T (bf16) in LDS per block.
// ---------------------------------------------------------------------------

#define B1_EPB 4096      // edges per histogram/bucket segment
#define BKT_SH 8         // 256 nodes per bucket
#define CHUNK  256       // staged edge indices per wave-chunk
#define PSTRIDE 512      // padded part row stride (coalesced reads)

typedef __attribute__((ext_vector_type(8))) short bf8;   // 8 x bf16 (4 VGPR)
typedef __attribute__((ext_vector_type(4))) float f4;    // MFMA accumulator
typedef __attribute__((ext_vector_type(2))) float f2v;   // cvt_pk_f32_fp8 out

__device__ __forceinline__ unsigned int f2bf(float x) {  // RNE
  unsigned int u = __float_as_uint(x);
  return (u + 0x7FFFu + ((u >> 16) & 1u)) >> 16;
}

// ---------------- CSR build ----------------
__global__ void bhist_cvt_k(const int* __restrict__ dsti, int* __restrict__ part,
                            int ne, const float* __restrict__ x,
                            unsigned int* __restrict__ xb, int n4,
                            int nbkt, int nseg) {
  __shared__ int lh[PSTRIDE];
  const int b = blockIdx.x, t = threadIdx.x;
  if (b < nseg) {
    for (int i = t; i < PSTRIDE; i += 256) lh[i] = 0;
    __syncthreads();
    const int base = b * B1_EPB;
    const int m = min(B1_EPB, ne - base);
    for (int i = t; i < m; i += 256) atomicAdd(&lh[dsti[base + i] >> BKT_SH], 1);
    __syncthreads();
    for (int i = t; i < PSTRIDE; i += 256) part[b * PSTRIDE + i] = lh[i];
  }
  const int gid = b * 256 + t, gst = gridDim.x * 256;
  for (int j = gid; j < n4; j += gst) {
    float4 v = ((const float4*)x)[j];
    int p = __builtin_amdgcn_cvt_pk_fp8_f32(v.x, v.y, 0, false);   // bytes 0,1
    p     = __builtin_amdgcn_cvt_pk_fp8_f32(v.z, v.w, p, true);    // bytes 2,3
    xb[j] = (unsigned int)p;
  }
}

// Single block, 512 threads: per-bucket totals (8-deep ILP, coalesced rows)
// then 512-wide scan -> bbase/bcur.
__global__ void bscan_k(const int* __restrict__ part, int* __restrict__ bbase,
                        int* __restrict__ bcur, int nbkt, int nseg, int ne) {
  __shared__ int sh[512];
  const int t = threadIdx.x;
  int s0 = 0, s1 = 0, s2 = 0, s3 = 0, s4 = 0, s5 = 0, s6 = 0, s7 = 0;
  int b = 0;
  for (; b + 7 < nseg; b += 8) {
    s0 += part[(b + 0) * PSTRIDE + t];
    s1 += part[(b + 1) * PSTRIDE + t];
    s2 += part[(b + 2) * PSTRIDE + t];
    s3 += part[(b + 3) * PSTRIDE + t];
    s4 += part[(b + 4) * PSTRIDE + t];
    s5 += part[(b + 5) * PSTRIDE + t];
    s6 += part[(b + 6) * PSTRIDE + t];
    s7 += part[(b + 7) * PSTRIDE + t];
  }
  for (; b < nseg; ++b) s0 += part[b * PSTRIDE + t];
  const int s = ((s0 + s1) + (s2 + s3)) + ((s4 + s5) + (s6 + s7));
  sh[t] = s; __syncthreads();
  for (int o = 1; o < 512; o <<= 1) {
    int v = (t >= o) ? sh[t - o] : 0; __syncthreads();
    sh[t] += v; __syncthreads();
  }
  if (t < nbkt) { int e = sh[t] - s; bbase[t] = e; bcur[t] = e; }
  if (t == 0) bbase[nbkt] = ne;
}

// 1024 threads: scatter packed (src<<8 | dst&255) into per-bucket regions.
__global__ void bucket_k(const int* __restrict__ srci, const int* __restrict__ dsti,
                         const int* __restrict__ part, int* __restrict__ bcur,
                         unsigned int* __restrict__ ebuf, int ne, int nbkt) {
  __shared__ int lcur[512], lbase[512];
  const int t = threadIdx.x;
  const int base = blockIdx.x * B1_EPB;
  const int m = min(B1_EPB, ne - base);
  for (int i = t; i < nbkt; i += 1024) {
    const int c = part[blockIdx.x * PSTRIDE + i];
    lbase[i] = c ? atomicAdd(&bcur[i], c) : 0;
    lcur[i] = 0;
  }
  __syncthreads();
  for (int i = t; i < m; i += 1024) {
    const int s = srci[base + i], d = dsti[base + i];
    const int b = d >> BKT_SH;
    const int p = lbase[b] + atomicAdd(&lcur[b], 1);
    ebuf[p] = ((unsigned)s << 8) | (unsigned)(d & ((1 << BKT_SH) - 1));
  }
}

// 1024 threads, one block per 256-node bucket: LDS hist of (dst&255) ->
// 256-wide scan (threads <256) -> row_off + scatter src into ssrc region.
__global__ void fillb_k(const unsigned int* __restrict__ ebuf,
                        const int* __restrict__ bbase,
                        int* __restrict__ row_off, int* __restrict__ ssrc,
                        int n, int ne) {
  __shared__ int lcnt[256], lpre[256], lcur[256];
  const int b = blockIdx.x, t = threadIdx.x;
  const int v0 = b << BKT_SH;
  const int nv = min(1 << BKT_SH, n - v0);
  const int start = bbase[b], end = bbase[b + 1];
  if (t < 256) lcnt[t] = 0;
  __syncthreads();
  for (int i = start + t; i < end; i += 1024)
    atomicAdd(&lcnt[ebuf[i] & ((1 << BKT_SH) - 1)], 1);
  __syncthreads();
  int x = 0;
  if (t < 256) { x = lcnt[t]; lpre[t] = x; }
  __syncthreads();
  for (int o = 1; o < 256; o <<= 1) {
    int v = 0;
    if (t < 256 && t >= o) v = lpre[t - o];
    __syncthreads();
    if (t < 256) lpre[t] += v;
    __syncthreads();
  }
  if (t < 256) {
    const int excl = start + lpre[t] - x;
    lcur[t] = excl;
    if (t < nv) row_off[v0 + t] = excl;
    if (t == 0) row_off[v0 + nv] = end;   // == next bucket's base (or ne)
  }
  __syncthreads();
  for (int i = start + t; i < end; i += 1024) {
    const unsigned int e = ebuf[i];
    const int p = atomicAdd(&lcur[e & ((1 << BKT_SH) - 1)], 1);
    ssrc[p] = (int)(e >> 8);
  }
}

// ---------------- fused gather + MFMA GEMM (+relu | +log_softmax) ----------
// 2 tiles/wave, software-pipelined row_off + first-chunk prefetch; uint2 8B
// fp8 loads, 8 lanes/row, 16 edges in flight; halves merged by shfl_xor(8).
// C layout: col = lane&15, row = quad*4 + reg.
template <int DOUT, bool LS>
__launch_bounds__(256, 4)
__global__ void fused_k(const unsigned char* __restrict__ in,
                        const int* __restrict__ row_off, const int* __restrict__ ssrc,
                        const float* __restrict__ Wm, const float* __restrict__ bin,
                        void* __restrict__ outp, int n) {
  constexpr int NT = (DOUT + 15) / 16;
  const int lane  = threadIdx.x & 63;
  const int wslot = threadIdx.x >> 6;
  const int quad  = lane >> 4;
  const int f16i  = lane & 15;
  const int hw    = (f16i >> 3) & 1;   // half within quarter (edge parity)
  const int j8    = f16i & 7;          // uint2 index within row (feats 8*j8..+7)

  __shared__ char rows_raw[4][16 * 144];
  __shared__ int  sidx[4][CHUNK];
  __shared__ unsigned short Wt[64 * 72];   // [c][k] bf16, 72-short (144B) rows
  char* my  = rows_raw[wslot];
  int*  sid = sidx[wslot];

  // ---- stage W^T -> LDS (once per block); zero-fill pads c >= DOUT ----
  {
    const int t = threadIdx.x;
    for (int i = t; i < 64 * 72; i += 256) Wt[i] = 0;
    __syncthreads();
    for (int i = t; i < 64 * DOUT; i += 256) {
      const int k = i / DOUT, c = i - k * DOUT;   // Wm row-major [64][DOUT]
      Wt[c * 72 + k] = (unsigned short)f2bf(Wm[i]);
    }
  }
  float bc[NT];
#pragma unroll
  for (int t = 0; t < NT; ++t) {
    const int c = t * 16 + f16i;
    bc[t] = (c < DOUT) ? bin[c] : 0.f;
  }
  __syncthreads();

  const uint2* in2 = (const uint2*)in;     // fp8 row = 8 x uint2 (64B)
  const int wid = (int)((blockIdx.x * blockDim.x + threadIdx.x) >> 6);
  const int nwv = (int)((gridDim.x * blockDim.x) >> 6);
  const int ntiles = (n + 15) >> 4;

  bool have_pref = false;                  // sid holds next tile's chunk 0?
  int ro_l = (wid < ntiles)
                 ? row_off[min((wid << 4) + min(lane, 16), n)] : 0;

  for (int tile = wid; tile < ntiles; tile += nwv) {
    const int tnext = tile + nwv;
    int ro_next = 0;
    if (tnext < ntiles)                    // issue early; consumed late
      ro_next = row_off[min((tnext << 4) + min(lane, 16), n)];

    const int v0 = tile << 4;
    const int base     = __shfl(ro_l, 0, 64);
    const int tile_end = __shfl(ro_l, 16, 64);
    int ns[4], nE[4];
#pragma unroll
    for (int r = 0; r < 4; ++r) {
      const int m = quad * 4 + r;
      ns[r] = __shfl(ro_l, m, 64);
      nE[r] = __shfl(ro_l, m + 1, 64);
    }

    float acc[4][8];
#pragma unroll
    for (int r = 0; r < 4; ++r)
#pragma unroll
      for (int i = 0; i < 8; ++i) acc[r][i] = 0.f;

    for (int off = base; off < tile_end; off += CHUNK) {
      const int cend = min(tile_end, off + CHUNK);
      const int nL = cend - off;
      if (!(have_pref && off == base)) {   // chunk 0 may be pre-staged
#pragma unroll
        for (int k = 0; k < CHUNK / 64; ++k) {
          const int p = off + lane + k * 64;
          if (p < cend) sid[lane + k * 64] = ssrc[p];
        }
      }
      asm volatile("s_waitcnt lgkmcnt(0)" ::: "memory");   // cross-lane LDS RAW

#pragma unroll
      for (int r = 0; r < 4; ++r) {
        const int ls = max(ns[r], off), le = min(nE[r], cend);
        for (int c = ls; c < le; c += 16) {
          uint2 q[8];
#pragma unroll
          for (int k = 0; k < 8; ++k) {
            const int e = c + (k << 1) + hw;             // 16 edges in flight
            const int lofs = min(e - off, nL - 1);       // clamp LDS read
            const int s = sid[lofs];                      // 8-lane broadcast
            q[k] = (e < le) ? in2[(size_t)s * 8 + j8]
                            : make_uint2(0u, 0u);        // fp8 0x00 == 0.0
          }
#pragma unroll
          for (int k = 0; k < 8; ++k) {
            f2v u;
            u = __builtin_amdgcn_cvt_pk_f32_fp8((int)q[k].x, false);
            acc[r][0] += u.x; acc[r][1] += u.y;
            u = __builtin_amdgcn_cvt_pk_f32_fp8((int)q[k].x, true);
            acc[r][2] += u.x; acc[r][3] += u.y;
            u = __builtin_amdgcn_cvt_pk_f32_fp8((int)q[k].y, false);
            acc[r][4] += u.x; acc[r][5] += u.y;
            u = __builtin_amdgcn_cvt_pk_f32_fp8((int)q[k].y, true);
            acc[r][6] += u.x; acc[r][7] += u.y;
          }
        }
      }
    }

    // ---- prefetch next tile's first index chunk (hides under epilogue) ----
    bool pref_ok = false;
    if (tnext < ntiles) {
      const int base_n = __shfl(ro_next, 0, 64);
      const int tend_n = __shfl(ro_next, 16, 64);
      const int cend_n = min(tend_n, base_n + CHUNK);
#pragma unroll
      for (int k = 0; k < CHUNK / 64; ++k) {
        const int p = base_n + lane + k * 64;
        if (p < cend_n) sid[lane + k * 64] = ssrc[p];
      }
      pref_ok = true;
    }

    // merge halves + pack bf16 rows -> LDS (8 lanes write 16B = 128B row)
#pragma unroll
    for (int r = 0; r < 4; ++r) {
#pragma unroll
      for (int i = 0; i < 8; ++i) acc[r][i] += __shfl_xor(acc[r][i], 8, 64);
      if (hw == 0) {
        const int m = quad * 4 + r;
        uint4 p;
        p.x = f2bf(acc[r][0]) | (f2bf(acc[r][1]) << 16);
        p.y = f2bf(acc[r][2]) | (f2bf(acc[r][3]) << 16);
        p.z = f2bf(acc[r][4]) | (f2bf(acc[r][5]) << 16);
        p.w = f2bf(acc[r][6]) | (f2bf(acc[r][7]) << 16);
        *(uint4*)(my + m * 144 + j8 * 16) = p;
      }
    }
    asm volatile("s_waitcnt lgkmcnt(0)" ::: "memory");   // cross-lane LDS RAW

    // ---- MFMA: [16 x 64] @ [64 x DOUT], B fragments from LDS W^T ----
    bf8 a0 = *(const bf8*)(my + f16i * 144 + quad * 16);        // K 0..31
    bf8 a1 = *(const bf8*)(my + f16i * 144 + quad * 16 + 64);   // K 32..63
    f4 acc2[NT];
#pragma unroll
    for (int t = 0; t < NT; ++t) {
      const unsigned short* wp = Wt + (t * 16 + f16i) * 72 + quad * 8;
      bf8 w0 = *(const bf8*)(wp);
      bf8 w1 = *(const bf8*)(wp + 32);
      f4 z = {0.f, 0.f, 0.f, 0.f};
      acc2[t] = __builtin_amdgcn_mfma_f32_16x16x32_bf16(a0, w0, z, 0, 0, 0);
      acc2[t] = __builtin_amdgcn_mfma_f32_16x16x32_bf16(a1, w1, acc2[t], 0, 0, 0);
    }

    // ---- epilogue ----
    if (!LS) {
      unsigned char* ob = (unsigned char*)outp;
#pragma unroll
      for (int t = 0; t < NT; ++t)
#pragma unroll
        for (int j = 0; j < 4; ++j) {
          const int v = v0 + quad * 4 + j;
          if (v < n) {
            float val = fmaxf(acc2[t][j] + bc[t], 0.f);
            int pk = __builtin_amdgcn_cvt_pk_fp8_f32(val, val, 0, false);
            ob[(size_t)v * 64 + t * 16 + f16i] = (unsigned char)(pk & 0xFF);
          }
        }
    } else {
      float* ob = (float*)outp;
      float val[NT][4];
#pragma unroll
      for (int t = 0; t < NT; ++t)
#pragma unroll
        for (int j = 0; j < 4; ++j) val[t][j] = acc2[t][j] + bc[t];
#pragma unroll
      for (int j = 0; j < 4; ++j) {
        float mx = -INFINITY;
#pragma unroll
        for (int t = 0; t < NT; ++t)
          if (t * 16 + f16i < DOUT) mx = fmaxf(mx, val[t][j]);
#pragma unroll
        for (int o = 1; o <= 8; o <<= 1) mx = fmaxf(mx, __shfl_xor(mx, o, 64));
        float sm = 0.f;
#pragma unroll
        for (int t = 0; t < NT; ++t)
          if (t * 16 + f16i < DOUT) sm += __expf(val[t][j] - mx);
#pragma unroll
        for (int o = 1; o <= 8; o <<= 1) sm += __shfl_xor(sm, o, 64);
        const float lse = mx + __logf(sm);
        const int v = v0 + quad * 4 + j;
        if (v < n) {
#pragma unroll
          for (int t = 0; t < NT; ++t) {
            const int c = t * 16 + f16i;
            if (c < DOUT) ob[(size_t)v * DOUT + c] = val[t][j] - lse;
          }
        }
      }
    }

    have_pref = pref_ok;
    ro_l = ro_next;
  }
}

extern "C" void kernel_launch(void* const* d_in, const int* in_sizes, int n_in,
                              void* d_out, int out_size, void* d_ws, size_t ws_size,
                              hipStream_t stream) {
  const float* x  = (const float*)d_in[0];
  const int*   ei = (const int*)d_in[1];   // [2, E] int32, row-major
  const float* W1 = (const float*)d_in[2];
  const float* b1 = (const float*)d_in[3];
  const float* W2 = (const float*)d_in[4];
  const float* b2 = (const float*)d_in[5];
  const float* W3 = (const float*)d_in[6];
  const float* b3 = (const float*)d_in[7];
  float* outp = (float*)d_out;

  const int n  = in_sizes[0] / 64;   // 100000
  const int ne = in_sizes[1] / 2;    // 800000
  const int* srci = ei;
  const int* dsti = ei + ne;
  const int nbkt = (n + (1 << BKT_SH) - 1) >> BKT_SH;   // 391
  const int nseg = (ne + B1_EPB - 1) / B1_EPB;          // 196

  const size_t N64 = (size_t)n * 64;              // bytes per fp8 feature plane
  unsigned char* xb   = (unsigned char*)d_ws;     // N*64 fp8
  unsigned char* bufA = xb + N64;                 // N*64 fp8 (h1)
  unsigned char* bufB = bufA + N64;               // N*64 fp8 (h2)
  unsigned int* ebuf = (unsigned int*)(bufB + N64);  // E packed (src<<8|dst&255)
  int* row_off  = (int*)(ebuf + ne);              // N+1
  int* part     = row_off + n + 1;                // nseg*PSTRIDE
  int* bbase    = part + nseg * PSTRIDE;          // nbkt+1
  int* bcur     = bbase + nbkt + 1;               // nbkt
  int* ssrc     = bcur + nbkt;                    // E

  const int TB = 256;
  const int fus_blocks = 784;   // 3136 waves, all co-resident; 2 tiles/wave

  // ---- CSR build + x->fp8 (4 dispatches) ----
  bhist_cvt_k<<<784, TB, 0, stream>>>(dsti, part, ne, x, (unsigned int*)xb,
                                      (int)(N64 / 4), nbkt, nseg);
  bscan_k<<<1, 512, 0, stream>>>(part, bbase, bcur, nbkt, nseg, ne);
  bucket_k<<<nseg, 1024, 0, stream>>>(srci, dsti, part, bcur, ebuf, ne, nbkt);
  fillb_k<<<nbkt, 1024, 0, stream>>>(ebuf, bbase, row_off, ssrc, n, ne);

  // ---- fused layers ----
  fused_k<64, false><<<fus_blocks, TB, 0, stream>>>(xb,   row_off, ssrc, W1, b1, bufA, n);
  fused_k<64, false><<<fus_blocks, TB, 0, stream>>>(bufA, row_off, ssrc, W2, b2, bufB, n);
  fused_k<47, true ><<<fus_blocks, TB, 0, stream>>>(bufB, row_off, ssrc, W3, b3, outp, n);
}